// Round 7
// baseline (344.098 us; speedup 1.0000x reference)
//
#include <hip/hip_runtime.h>
#include <stdint.h>

// Shapes from reference
#define Bn    4
#define Cn    720
#define Hn    128
#define Wn    128
#define Pn    9
#define OFFn  80          // Cn / Pn
#define HWn   16384       // Hn * Wn (= 2^14)
#define TPB   1024        // 16 waves/block
#define NBLK  512         // persistent, 2 blocks/CU (64 KB LDS each) -> 32 waves/CU
#define PLANES   (Bn * Cn)      // 2880 planes; group id = plane/80 == b*Pn+p
#define PER_XCD  (PLANES / 8)   // 360 planes per XCD
#define NSLOT    (NBLK / 8)     // 64 blocks per XCD

// ---------------------------------------------------------------------------
// Async 16B global->LDS (global_load_lds_dwordx4): per-lane GLOBAL address,
// wave-uniform LDS base, HW writes lane i at ldsbase + i*16 (linear dest).
// ---------------------------------------------------------------------------
__device__ __forceinline__ void async_ld16(const void* g, void* l)
{
    __builtin_amdgcn_global_load_lds(
        (__attribute__((address_space(1))) void*)(g),
        (__attribute__((address_space(3))) void*)(l),
        16, 0, 0);
}

// Stage one 64 KB plane: 64 segments of 1 KB (64 lanes x 16 B); wave w issues
// segments 4w..4w+3 (4 vmcnt ops per wave). Fully async; caller waits.
__device__ __forceinline__ void stage_plane_async(
    const float* __restrict__ src, float* dstLDS, int tid)
{
    const int wave = tid >> 6;
    const int lane = tid & 63;
    #pragma unroll
    for (int k = 0; k < 4; ++k) {
        const int seg = wave * 4 + k;
        async_ld16(src + seg * 256 + lane * 4, dstLDS + seg * 256);
    }
}

// Per-thread gather records for a (b,p) group: 16 positions -> 48 VGPRs.
__device__ __forceinline__ void load_records(
    const float* __restrict__ loc, int gid, int tid,
    int (&rbase)[4][4], float (&rdy)[4][4], float (&rdx)[4][4])
{
    const float4* ly4 = (const float4*)(loc + (size_t)(2 * gid) * HWn);
    const float4* lx4 = ly4 + HWn / 4;
    #pragma unroll
    for (int k = 0; k < 4; ++k) {
        const int q = tid + k * TPB;
        const float4 yv = ly4[q];
        const float4 xv = lx4[q];
        #pragma unroll
        for (int j = 0; j < 4; ++j) {
            const float yq = (&yv.x)[j];
            const float xq = (&xv.x)[j];
            const float y0f = floorf(yq);
            const float x0f = floorf(xq);
            rdy[k][j] = yq - y0f;
            rdx[k][j] = xq - x0f;
            // location = uniform[0,127): strictly in-bounds; clamp is
            // defensive only (bounds the LDS address).
            const int y0 = min(max((int)y0f, 0), Hn - 2);
            const int x0 = min(max((int)x0f, 0), Wn - 2);
            rbase[k][j] = y0 * Wn + x0;
        }
    }
}

// ---------------------------------------------------------------------------
// Session evidence (6 rounds): the ONLY lever that moved duration is
// waves/CU. R0 (16 w/CU, serial stage) = 121 us; R2 (32 w/CU, serial stage)
// ~ 103 us (reconstructed: bench = ~216 us fixed harness fills + hot);
// every 16-wave persistent/double-buffered/counted-vmcnt variant = 119-121.
// Latency-bound kernel, all pipes <50%: TLP is what hides latency, and
// double-buffering (128 KB -> 1 block/CU -> 16 waves) trades it away.
//
// Round 7 = R2 geometry (2 blocks/CU x 16 waves, single 64 KB buffer, serial
// stage per channel; cross-block TLP provides stage/gather overlap) + the
// proven-cheap upgrades: persistent blocks (5-6 consecutive channels) with
// register records computed once per group (kills R2's 38%-VALU redundancy;
// 52 VGPR fits the 64 cap of 8 waves/SIMD), XCD-chunked plane assignment
// (FETCH stays ~97 MB), raw s_barrier after gather (stores NOT drained at
// the barrier; they retire under the next stage's vmcnt(0), which is itself
// covered by stage latency).
//
// Per channel: [gather+store from buf] -> s_barrier -> [stage next plane] ->
// vmcnt(0) -> s_barrier. Waves' own ds_reads are drained by data dependence
// (FMAs consume them before the stores), so the post-gather barrier needs no
// waitcnt.
// ---------------------------------------------------------------------------
__global__ __launch_bounds__(TPB, 8) void dcn_tlp_kernel(
    const float* __restrict__ x,
    const float* __restrict__ loc,
    const float* __restrict__ bias,
    float* __restrict__ out)
{
    __shared__ float splane[HWn];    // 64 KB -> 2 blocks/CU

    const int g    = blockIdx.x;
    const int xcd  = g & 7;          // consecutive blocks round-robin XCDs
    const int slot = g >> 3;         // 0..63 within XCD
    const int begin = xcd * PER_XCD + (slot * PER_XCD) / NSLOT;
    const int end   = xcd * PER_XCD + ((slot + 1) * PER_XCD) / NSLOT;
    const int tid   = threadIdx.x;

    int   rbase[4][4];
    float rdy[4][4];
    float rdx[4][4];
    int prev_gid = -1;

    // Prologue: stage first plane.
    stage_plane_async(x + (size_t)begin * HWn, splane, tid);
    asm volatile("s_waitcnt vmcnt(0)" ::: "memory");
    __builtin_amdgcn_sched_barrier(0);
    __builtin_amdgcn_s_barrier();
    __builtin_amdgcn_sched_barrier(0);

    for (int bc = begin; bc < end; ++bc) {
        const int gid = bc / OFFn;
        if (gid != prev_gid) {
            prev_gid = gid;
            load_records(loc, gid, tid, rbase, rdy, rdx);
        }

        const int   c  = bc % Cn;
        const float bv = bias[c];
        float4* ob4 = (float4*)(out + (size_t)bc * HWn);

        // ---- Gather: 16 positions/thread, records in regs ----
        #pragma unroll
        for (int k = 0; k < 4; ++k) {
            const int q = tid + k * TPB;
            float4 r;
            #pragma unroll
            for (int j = 0; j < 4; ++j) {
                const float* r0 = splane + rbase[k][j];
                const float v00 = r0[0];
                const float v01 = r0[1];
                const float v10 = r0[Wn];
                const float v11 = r0[Wn + 1];
                const float dy = rdy[k][j];
                const float dx = rdx[k][j];
                const float omdy = 1.f - dy;
                const float omdx = 1.f - dx;
                (&r.x)[j] = omdy * (omdx * v00 + dx * v01)
                          + dy   * (omdx * v10 + dx * v11) + bv;
            }
            ob4[q] = r;
        }

        // All waves done reading splane (ds results consumed by the FMAs
        // feeding the stores) -> raw barrier, stores stay in flight.
        __builtin_amdgcn_sched_barrier(0);
        __builtin_amdgcn_s_barrier();
        __builtin_amdgcn_sched_barrier(0);

        if (bc + 1 < end) {
            stage_plane_async(x + (size_t)(bc + 1) * HWn, splane, tid);
            // Drains stage (and, incidentally, this channel's stores --
            // both covered by the stage's HBM/L3 latency).
            asm volatile("s_waitcnt vmcnt(0)" ::: "memory");
            __builtin_amdgcn_sched_barrier(0);
            __builtin_amdgcn_s_barrier();
            __builtin_amdgcn_sched_barrier(0);
        }
    }
}

extern "C" void kernel_launch(void* const* d_in, const int* in_sizes, int n_in,
                              void* d_out, int out_size, void* d_ws, size_t ws_size,
                              hipStream_t stream)
{
    const float* x    = (const float*)d_in[0];
    const float* loc  = (const float*)d_in[1];
    const float* bias = (const float*)d_in[2];
    float* out        = (float*)d_out;

    dim3 grid(NBLK);   // 512 persistent blocks, 2 per CU -> 32 waves/CU
    dcn_tlp_kernel<<<grid, TPB, 0, stream>>>(x, loc, bias, out);
}